// Round 9
// baseline (365.540 us; speedup 1.0000x reference)
//
#include <hip/hip_runtime.h>

// GCN layer: out = relu(segment_sum(edge_val * (x@W + b)[edge_col] -> edge_row))
// N=100000 nodes, E=1600000 edges, 256 -> 128 features, fp32 in/out.
//
// Round 15: overlap gemm with the CSR build via blockIdx-partitioned
// co-launch. r14 accounting: aggregate=64.5us but total-aggregate=267us
// spread over 7 sub-64us dispatches -- gemm (~60us, MFMA/HBM pipes) runs
// strictly serialized before/through a CSR chain (atomic/LDS pipes) it is
// completely independent of. Streams+events are banned (graph capture), so
// each CSR stage kernel carries a slice of gemm's tile range as extra
// blocks: launch = {stage blocks} U {gemm blocks}. Stream order preserves
// bhist->bscan->bin->place; within a launch the two halves co-run on
// different pipes. LDS aliased via dynamic shared (32KB = gemm dbuf).
//   k1 = bhist(256 blk) + gemm tiles [0,1600)    (320 blk)
//   k2 = bscan(1 blk)   + gemm tiles [1600,1900) ( 64 blk)
//   k3 = bin  (256 blk) + gemm tiles [1900,4700) (560 blk)
//   k4 = place(1024 blk)+ gemm tiles [4700,6250) (312 blk)
// gemm core (r9), CSR params (r14: kNB=1024), aggregate (r12) unchanged.

constexpr int kNodes = 100000;
constexpr int kEdges = 1600000;
constexpr int kInF   = 256;
constexpr int kOutF  = 128;
constexpr int kTiles = kNodes / 16;                 // 6250

constexpr int kNB  = 1024;                          // buckets
constexpr int kRB  = 98;                            // rows/bucket (1024*98 >= N)
constexpr int kCap = 1792;                          // LDS-staged edges/bucket
constexpr int kBinBlocks = 256;
constexpr int kEPB = kEdges / kBinBlocks;           // 6250 edges/block

constexpr int kTileCap = 1024;                      // staged edges per 16-node agg tile

// gemm tile ranges + gemm block counts per co-launch
constexpr int kC1 = 1600, kC2 = 1900, kC3 = 4700, kC4 = kTiles;
constexpr int kG1 = 320, kG2 = 64, kG3 = 560, kG4 = 312;
constexpr int kSmem = 32768;                        // max(gemm 32KB, stages <=15.3KB)

typedef __attribute__((ext_vector_type(8))) short short8;
typedef __attribute__((ext_vector_type(8))) unsigned short ush8;
typedef __attribute__((ext_vector_type(4))) float floatx4;

__device__ inline unsigned short f2bf_rne(float f) {
    unsigned int u = __float_as_uint(f);
    unsigned int r = u + 0x7FFFu + ((u >> 16) & 1u);
    return (unsigned short)(r >> 16);
}
__device__ inline float bf2f(unsigned short h) {
    return __uint_as_float(((unsigned int)h) << 16);
}

__device__ inline short8 cvt8_bf16(const float4 a, const float4 b) {
    union { short8 s; unsigned int u[4]; } r;
    asm("v_cvt_pk_bf16_f32 %0, %1, %2" : "=v"(r.u[0]) : "v"(a.x), "v"(a.y));
    asm("v_cvt_pk_bf16_f32 %0, %1, %2" : "=v"(r.u[1]) : "v"(a.z), "v"(a.w));
    asm("v_cvt_pk_bf16_f32 %0, %1, %2" : "=v"(r.u[2]) : "v"(b.x), "v"(b.y));
    asm("v_cvt_pk_bf16_f32 %0, %1, %2" : "=v"(r.u[3]) : "v"(b.z), "v"(b.w));
    return r.s;
}

__device__ inline void gload_lds16(const void* g, void* l) {
    __builtin_amdgcn_global_load_lds(
        (const __attribute__((address_space(1))) unsigned int*)g,
        (__attribute__((address_space(3))) unsigned int*)l,
        16, 0, 0);
}

// ---------------------------------------------------------------------------
// GEMM body (r9 core): processes tiles [t0,t1) grid-strided over nG blocks,
// this block being gblk. lbuf = 2 x 4096 floats (32KB dynamic LDS).
// ---------------------------------------------------------------------------
__device__ inline void gemm_body(const float* __restrict__ x,
                                 const float* __restrict__ W,
                                 const float* __restrict__ b,
                                 unsigned short* __restrict__ support,
                                 float* lbuf, int t0, int t1, int gblk, int nG) {
    const int lane = threadIdx.x & 63;
    const int wv   = threadIdx.x >> 6;
    const int rowl = lane & 15;
    const int quad = lane >> 4;
    const int colbase = wv * 32;

    short8 bfrag[2][8];
#pragma unroll
    for (int ct = 0; ct < 2; ++ct) {
        const int col = colbase + ct * 16 + rowl;
#pragma unroll
        for (int kc = 0; kc < 8; ++kc) {
            const int kb = kc * 32 + quad * 8;
            short8 f;
#pragma unroll
            for (int j = 0; j < 8; ++j)
                f[j] = (short)f2bf_rne(W[(size_t)(kb + j) * kOutF + col]);
            bfrag[ct][kc] = f;
        }
    }
    const float bias0 = b[colbase + rowl];
    const float bias1 = b[colbase + 16 + rowl];

    float* bcur = lbuf;
    float* bnxt = lbuf + 4096;

#define GEMM_STAGE(dst_, tile_)                                                   \
    do {                                                                          \
        const float* tb_ = x + (size_t)(tile_) * 16 * kInF;                       \
        _Pragma("unroll")                                                         \
        for (int i_ = 0; i_ < 4; ++i_) {                                          \
            const int row_ = i_ * 4 + wv;                                         \
            gload_lds16(tb_ + (size_t)row_ * kInF + ((lane ^ (row_ & 7)) << 2),   \
                        (dst_) + (row_ << 8));                                    \
        }                                                                         \
    } while (0)

    int t = t0 + gblk;
    if (t < t1) GEMM_STAGE(bcur, t);

    for (; t < t1; t += nG) {
        const int tn = t + nG;
        asm volatile("s_waitcnt vmcnt(0)" ::: "memory");
        __syncthreads();
        if (tn < t1) GEMM_STAGE(bnxt, tn);

        const int r0 = t * 16;
        const float* base = bcur + (rowl << 8);
        const int rsw = rowl & 7;
        floatx4 acc0 = {0.f, 0.f, 0.f, 0.f};
        floatx4 acc1 = {0.f, 0.f, 0.f, 0.f};
#pragma unroll
        for (int kc = 0; kc < 8; ++kc) {
            const int g0 = (kc << 3) + (quad << 1);
            const float4 v0 = *reinterpret_cast<const float4*>(base + ((g0 ^ rsw) << 2));
            const float4 v1 = *reinterpret_cast<const float4*>(base + (((g0 + 1) ^ rsw) << 2));
            const short8 a = cvt8_bf16(v0, v1);
            acc0 = __builtin_amdgcn_mfma_f32_16x16x32_bf16(a, bfrag[0][kc], acc0, 0, 0, 0);
            acc1 = __builtin_amdgcn_mfma_f32_16x16x32_bf16(a, bfrag[1][kc], acc1, 0, 0, 0);
        }
#pragma unroll
        for (int reg = 0; reg < 4; ++reg) {
            const size_t rbase = (size_t)(r0 + quad * 4 + reg) * kOutF + colbase;
            support[rbase + rowl]      = f2bf_rne(acc0[reg] + bias0);
            support[rbase + 16 + rowl] = f2bf_rne(acc1[reg] + bias1);
        }
        float* tmp = bcur; bcur = bnxt; bnxt = tmp;
    }
#undef GEMM_STAGE
}

// ---------------------------------------------------------------------------
// CSR stage bodies (r14 logic, smem passed in).
// ---------------------------------------------------------------------------
__device__ inline void bhist_body(const int* __restrict__ erow,
                                  int* __restrict__ bucket_tot, int* cnt) {
    const int tid = threadIdx.x;
    for (int i = tid; i < kNB; i += 256) cnt[i] = 0;
    __syncthreads();
    const int eb0 = blockIdx.x * kEPB;
    const int eb1 = min(eb0 + kEPB, kEdges);
    for (int e = eb0 + tid; e < eb1; e += 256)
        atomicAdd(&cnt[(unsigned int)erow[e] / (unsigned int)kRB], 1);
    __syncthreads();
    for (int i = tid; i < kNB; i += 256) {
        const int c = cnt[i];
        if (c) atomicAdd(&bucket_tot[i], c);
    }
}

__device__ inline void bscan_body(const int* __restrict__ bucket_tot,
                                  int* __restrict__ bucket_base,
                                  int* __restrict__ cursor,
                                  int* __restrict__ row_start, int* s) {
    const int tid = threadIdx.x;
    int t[4];
#pragma unroll
    for (int j = 0; j < 4; ++j) {
        const int idx = tid + j * 256;
        t[j] = bucket_tot[idx];
        s[idx] = t[j];
    }
    __syncthreads();
    for (int off = 1; off < kNB; off <<= 1) {
        int v[4];
#pragma unroll
        for (int j = 0; j < 4; ++j) {
            const int idx = tid + j * 256;
            v[j] = (idx >= off) ? s[idx - off] : 0;
        }
        __syncthreads();
#pragma unroll
        for (int j = 0; j < 4; ++j) s[tid + j * 256] += v[j];
        __syncthreads();
    }
#pragma unroll
    for (int j = 0; j < 4; ++j) {
        const int idx = tid + j * 256;
        const int excl = s[idx] - t[j];
        bucket_base[idx] = excl;
        cursor[idx]      = excl;
    }
    if (tid == 255) {
        bucket_base[kNB]  = kEdges;
        row_start[kNodes] = kEdges;
    }
}

__device__ inline void bin_body(const int* __restrict__ erow,
                                const int* __restrict__ ecol,
                                const float* __restrict__ eval,
                                int* __restrict__ cursor,
                                int2* __restrict__ packed, int* cnt, int* rk) {
    const int tid = threadIdx.x;
    const int eb0 = blockIdx.x * kEPB;
    const int eb1 = min(eb0 + kEPB, kEdges);
    for (int i = tid; i < kNB; i += 256) { cnt[i] = 0; rk[i] = 0; }
    __syncthreads();
#pragma unroll 4
    for (int e = eb0 + tid; e < eb1; e += 256)
        atomicAdd(&cnt[(unsigned int)erow[e] / (unsigned int)kRB], 1);
    __syncthreads();
    for (int i = tid; i < kNB; i += 256) {
        const int c = cnt[i];
        cnt[i] = c ? atomicAdd(&cursor[i], c) : 0;
    }
    __syncthreads();
#pragma unroll 4
    for (int e = eb0 + tid; e < eb1; e += 256) {
        const int r = erow[e];
        const unsigned int bk = (unsigned int)r / (unsigned int)kRB;
        const int rl = r - (int)bk * kRB;
        const int pos = cnt[bk] + atomicAdd(&rk[bk], 1);
        packed[pos] = make_int2((rl << 17) | ecol[e], __float_as_int(eval[e]));
    }
}

__device__ inline void place_body(const int* __restrict__ bucket_base,
                                  int* __restrict__ row_start,
                                  int2* __restrict__ packed, char* smem) {
    int2* st   = (int2*)smem;                       // 14,336 B
    int*  s    = (int*)(smem + 14336);              //    512 B
    int*  rcur = (int*)(smem + 14848);              //    392 B
    const int bk = blockIdx.x;
    const int r0 = bk * kRB;
    if (r0 >= kNodes) return;
    const int r1 = min(r0 + kRB, kNodes);
    const int NR = r1 - r0;
    const int bb = bucket_base[bk];
    const int s1 = bucket_base[bk + 1];
    const int size   = s1 - bb;
    const int staged = min(size, kCap);
    const int tid = threadIdx.x;

    if (tid < 128) s[tid] = 0;
    __syncthreads();

    for (int i = tid; i < staged; i += 256) {
        const int2 p = packed[bb + i];
        st[i] = p;
        atomicAdd(&s[p.x >> 17], 1);
    }
    int2 tail[8];
    int  nt = 0;
    for (int i = kCap + tid; i < size; i += 256) {
        if (nt < 8) {
            tail[nt] = packed[bb + i];
            atomicAdd(&s[tail[nt].x >> 17], 1);
            ++nt;
        }
    }
    __syncthreads();

    for (int off = 1; off < 128; off <<= 1) {
        int v = 0;
        if (tid < 128 && tid >= off) v = s[tid - off];
        __syncthreads();
        if (tid < 128) s[tid] += v;
        __syncthreads();
    }
    if (tid < NR) {
        const int excl = tid ? s[tid - 1] : 0;
        row_start[r0 + tid] = bb + excl;
        rcur[tid] = excl;
    }
    __syncthreads();

    for (int i = tid; i < staged; i += 256) {
        const int2 p  = st[i];
        const int pos = bb + atomicAdd(&rcur[p.x >> 17], 1);
        packed[pos] = make_int2(p.x & 0x1FFFF, p.y);
    }
#pragma unroll
    for (int t = 0; t < 8; ++t) {
        if (t < nt) {
            const int2 p  = tail[t];
            const int pos = bb + atomicAdd(&rcur[p.x >> 17], 1);
            packed[pos] = make_int2(p.x & 0x1FFFF, p.y);
        }
    }
}

// ---------------------------------------------------------------------------
// Co-launch kernels: stage blocks first, gemm blocks after.
// ---------------------------------------------------------------------------
__global__ __launch_bounds__(256) void gcn_k1(const float* __restrict__ x,
                                              const float* __restrict__ W,
                                              const float* __restrict__ b,
                                              unsigned short* __restrict__ support,
                                              const int* __restrict__ erow,
                                              int* __restrict__ bucket_tot) {
    extern __shared__ char smem[];
    if (blockIdx.x < kBinBlocks)
        bhist_body(erow, bucket_tot, (int*)smem);
    else
        gemm_body(x, W, b, support, (float*)smem, 0, kC1, blockIdx.x - kBinBlocks, kG1);
}

__global__ __launch_bounds__(256) void gcn_k2(const float* __restrict__ x,
                                              const float* __restrict__ W,
                                              const float* __restrict__ b,
                                              unsigned short* __restrict__ support,
                                              const int* __restrict__ bucket_tot,
                                              int* __restrict__ bucket_base,
                                              int* __restrict__ cursor,
                                              int* __restrict__ row_start) {
    extern __shared__ char smem[];
    if (blockIdx.x == 0)
        bscan_body(bucket_tot, bucket_base, cursor, row_start, (int*)smem);
    else
        gemm_body(x, W, b, support, (float*)smem, kC1, kC2, blockIdx.x - 1, kG2);
}

__global__ __launch_bounds__(256) void gcn_k3(const float* __restrict__ x,
                                              const float* __restrict__ W,
                                              const float* __restrict__ b,
                                              unsigned short* __restrict__ support,
                                              const int* __restrict__ erow,
                                              const int* __restrict__ ecol,
                                              const float* __restrict__ eval,
                                              int* __restrict__ cursor,
                                              int2* __restrict__ packed) {
    extern __shared__ char smem[];
    if (blockIdx.x < kBinBlocks)
        bin_body(erow, ecol, eval, cursor, packed, (int*)smem, (int*)(smem + 4096));
    else
        gemm_body(x, W, b, support, (float*)smem, kC2, kC3, blockIdx.x - kBinBlocks, kG3);
}

__global__ __launch_bounds__(256) void gcn_k4(const float* __restrict__ x,
                                              const float* __restrict__ W,
                                              const float* __restrict__ b,
                                              unsigned short* __restrict__ support,
                                              const int* __restrict__ bucket_base,
                                              int* __restrict__ row_start,
                                              int2* __restrict__ packed) {
    extern __shared__ char smem[];
    if (blockIdx.x < kNB)
        place_body(bucket_base, row_start, packed, smem);
    else
        gemm_body(x, W, b, support, (float*)smem, kC3, kC4, blockIdx.x - kNB, kG4);
}

// ---------------------------------------------------------------------------
// Aggregate + ReLU (r12, unchanged).
// ---------------------------------------------------------------------------
__global__ __launch_bounds__(256) void gcn_aggregate(const int* __restrict__ row_start,
                                                     const int2* __restrict__ packed,
                                                     const unsigned short* __restrict__ support,
                                                     float* __restrict__ out) {
    __shared__ int2 ep[kTileCap];
    const int n0 = blockIdx.x * 16;
    const int e0 = row_start[n0];
    const int eN = row_start[n0 + 16] - e0;
    const int nStage = min(eN, kTileCap);
    for (int i = threadIdx.x; i < nStage; i += 256)
        ep[i] = packed[e0 + i];
    __syncthreads();

    const int n  = n0 + (threadIdx.x >> 4);
    const int f8 = (threadIdx.x & 15) * 8;
    const unsigned short* sb = support + f8;
    const int s0 = row_start[n]     - e0;
    const int s1 = row_start[n + 1] - e0;

    float acc[8];
#pragma unroll
    for (int j = 0; j < 8; ++j) acc[j] = 0.f;

    if (eN <= kTileCap) {
        int i = s0;
        for (; i + 7 < s1; i += 8) {
            int2 p[8];
#pragma unroll
            for (int k = 0; k < 8; ++k) p[k] = ep[i + k];
            ush8 g[8];
#pragma unroll
            for (int k = 0; k < 8; ++k)
                g[k] = *reinterpret_cast<const ush8*>(sb + (size_t)p[k].x * kOutF);
#pragma unroll
            for (int k = 0; k < 8; ++k) {
                const float v = __int_as_float(p[k].y);
#pragma unroll
                for (int j = 0; j < 8; ++j) acc[j] += v * bf2f(g[k][j]);
            }
        }
        for (; i < s1; ++i) {
            const int2 p = ep[i];
            const float v = __int_as_float(p.y);
            const ush8 g = *reinterpret_cast<const ush8*>(sb + (size_t)p.x * kOutF);
#pragma unroll
            for (int j = 0; j < 8; ++j) acc[j] += v * bf2f(g[j]);
        }
    } else {
        int i = s0;
        for (; i + 3 < s1; i += 4) {
            const int2 p0 = packed[e0 + i];
            const int2 p1 = packed[e0 + i + 1];
            const int2 p2 = packed[e0 + i + 2];
            const int2 p3 = packed[e0 + i + 3];
            const ush8 a0 = *reinterpret_cast<const ush8*>(sb + (size_t)p0.x * kOutF);
            const ush8 a1 = *reinterpret_cast<const ush8*>(sb + (size_t)p1.x * kOutF);
            const ush8 a2 = *reinterpret_cast<const ush8*>(sb + (size_t)p2.x * kOutF);
            const ush8 a3 = *reinterpret_cast<const ush8*>(sb + (size_t)p3.x * kOutF);
            const float v0 = __int_as_float(p0.y), v1 = __int_as_float(p1.y);
            const float v2 = __int_as_float(p2.y), v3 = __int_as_float(p3.y);
#pragma unroll
            for (int j = 0; j < 8; ++j) {
                acc[j] += v0 * bf2f(a0[j]);
                acc[j] += v1 * bf2f(a1[j]);
                acc[j] += v2 * bf2f(a2[j]);
                acc[j] += v3 * bf2f(a3[j]);
            }
        }
        for (; i < s1; ++i) {
            const int2 p = packed[e0 + i];
            const float v = __int_as_float(p.y);
            const ush8 a = *reinterpret_cast<const ush8*>(sb + (size_t)p.x * kOutF);
#pragma unroll
            for (int j = 0; j < 8; ++j) acc[j] += v * bf2f(a[j]);
        }
    }

    float4 o0 = make_float4(fmaxf(acc[0], 0.f), fmaxf(acc[1], 0.f),
                            fmaxf(acc[2], 0.f), fmaxf(acc[3], 0.f));
    float4 o1 = make_float4(fmaxf(acc[4], 0.f), fmaxf(acc[5], 0.f),
                            fmaxf(acc[6], 0.f), fmaxf(acc[7], 0.f));
    *reinterpret_cast<float4*>(out + (size_t)n * kOutF + f8)     = o0;
    *reinterpret_cast<float4*>(out + (size_t)n * kOutF + f8 + 4) = o1;
}

extern "C" void kernel_launch(void* const* d_in, const int* in_sizes, int n_in,
                              void* d_out, int out_size, void* d_ws, size_t ws_size,
                              hipStream_t stream) {
    const float* x    = (const float*)d_in[0];
    const int*   erow = (const int*)  d_in[1];
    const int*   ecol = (const int*)  d_in[2];
    const float* eval = (const float*)d_in[3];
    const float* W    = (const float*)d_in[4];
    const float* b    = (const float*)d_in[5];
    float* out = (float*)d_out;

    char* ws = (char*)d_ws;
    unsigned short* support = (unsigned short*)(ws);       // 25,600,000 B (row-major [N][128])
    int2* packed      = (int2*)(ws + 25600000);            // 12,800,000 B
    int*  row_start   = (int*) (ws + 38400000);            //    400,004 B
    int*  bucket_tot  = (int*) (ws + 38800008);            //      4,096 B
    int*  bucket_base = (int*) (ws + 38804104);            //      4,100 B
    int*  cursor      = (int*) (ws + 38808204);            //      4,096 B

    hipMemsetAsync(bucket_tot, 0, kNB * sizeof(int), stream);

    // co-launched: CSR stage + gemm tile slice (independent halves)
    gcn_k1<<<kBinBlocks + kG1, 256, kSmem, stream>>>(x, W, b, support, erow, bucket_tot);
    gcn_k2<<<1 + kG2,          256, kSmem, stream>>>(x, W, b, support, bucket_tot,
                                                     bucket_base, cursor, row_start);
    gcn_k3<<<kBinBlocks + kG3, 256, kSmem, stream>>>(x, W, b, support, erow, ecol, eval,
                                                     cursor, packed);
    gcn_k4<<<kNB + kG4,        256, kSmem, stream>>>(x, W, b, support, bucket_base,
                                                     row_start, packed);

    // aggregate + relu (needs support + CSR complete)
    gcn_aggregate<<<kTiles, 256, 0, stream>>>(row_start, packed, support, out);
}